// Round 5
// baseline (14582.869 us; speedup 1.0000x reference)
//
#include <hip/hip_runtime.h>

typedef unsigned short u16;
typedef unsigned int u32;
typedef unsigned long long u64;
typedef __attribute__((ext_vector_type(8))) short short8;
typedef __attribute__((ext_vector_type(4))) float f32x4;
typedef __attribute__((ext_vector_type(4))) u32 u32x4;
typedef __attribute__((ext_vector_type(2))) u32 u32x2;

#define DEV __device__ __forceinline__

DEV u16 f2b(float f) {
  u32 u = __builtin_bit_cast(u32, f);
  return (u16)((u + 0x7fffu + ((u >> 16) & 1u)) >> 16);  // RNE
}
DEV float b2f(u16 h) { u32 u = (u32)h << 16; return __builtin_bit_cast(float, u); }
DEV float sigm(float x) { return 1.0f / (1.0f + __expf(-x)); }

// ------------------------------------------------------------------
// Tiled bf16 MFMA GEMM core with reg-prefetch software pipeline.
// C[M,N] = A[M,K] @ Bt[N,K]^T, f32 accum. 256 threads, 4 waves 2x2.
// ------------------------------------------------------------------
template<int BM, int BN>
DEV void gemm_phase(const u16* __restrict__ A, const u16* __restrict__ Bt, int K,
                    u16* lA, u16* lB, int tid, int lane, int wm, int wn,
                    f32x4 (&acc)[BM/32][BN/32]) {
  constexpr int FM = BM / 32, FN = BN / 32;
  constexpr int CA = BM / 64, CB = BN / 64;  // 16B chunks per thread
  u32x4 ra[CA], rb[CB];
#pragma unroll
  for (int c = 0; c < CA; ++c) { int i = c * 256 + tid; ra[c] = *(const u32x4*)(A + (u64)(i >> 2) * K + (i & 3) * 8); }
#pragma unroll
  for (int c = 0; c < CB; ++c) { int i = c * 256 + tid; rb[c] = *(const u32x4*)(Bt + (u64)(i >> 2) * K + (i & 3) * 8); }
  for (int k0 = 0; k0 < K; k0 += 32) {
    __syncthreads();  // previous iter's frag reads done before overwrite
#pragma unroll
    for (int c = 0; c < CA; ++c) { int i = c * 256 + tid; *(u32x4*)(lA + i * 8) = ra[c]; }
#pragma unroll
    for (int c = 0; c < CB; ++c) { int i = c * 256 + tid; *(u32x4*)(lB + i * 8) = rb[c]; }
    __syncthreads();
    if (k0 + 32 < K) {  // prefetch next K-slice; latency hides under MFMA
#pragma unroll
      for (int c = 0; c < CA; ++c) { int i = c * 256 + tid; ra[c] = *(const u32x4*)(A + (u64)(i >> 2) * K + k0 + 32 + (i & 3) * 8); }
#pragma unroll
      for (int c = 0; c < CB; ++c) { int i = c * 256 + tid; rb[c] = *(const u32x4*)(Bt + (u64)(i >> 2) * K + k0 + 32 + (i & 3) * 8); }
    }
    short8 af[FM], bfr[FN];
#pragma unroll
    for (int fm = 0; fm < FM; ++fm)
      af[fm] = *(const short8*)(lA + (wm * (BM / 2) + fm * 16 + (lane & 15)) * 32 + (lane >> 4) * 8);
#pragma unroll
    for (int fn = 0; fn < FN; ++fn)
      bfr[fn] = *(const short8*)(lB + (wn * (BN / 2) + fn * 16 + (lane & 15)) * 32 + (lane >> 4) * 8);
#pragma unroll
    for (int fm = 0; fm < FM; ++fm)
#pragma unroll
      for (int fn = 0; fn < FN; ++fn)
        acc[fm][fn] = __builtin_amdgcn_mfma_f32_16x16x32_bf16(af[fm], bfr[fn], acc[fm][fn], 0, 0, 0);
  }
}

// VAR: 0=att1(bf16 out,+bias)  1=preds(masked f32 to out)
//      3=h0|c0                 5=pre(f32, +interleaved biases)
template<int BM, int BN, int VAR>
__launch_bounds__(256)
__global__ void gemm_k(const u16* __restrict__ A, const u16* __restrict__ Bt, int K,
                       int N,
                       const float* __restrict__ bias1, const float* __restrict__ bias2,
                       float* __restrict__ o1, float* __restrict__ o2,
                       u16* __restrict__ ob,
                       const int* __restrict__ caplen) {
  constexpr int FM = BM / 32, FN = BN / 32;
  __shared__ __align__(16) u16 lA[BM * 32];
  __shared__ __align__(16) u16 lB[BN * 32];
  const int tid = threadIdx.x, lane = tid & 63;
  const int wm = (tid >> 6) >> 1, wn = (tid >> 6) & 1;
  const int m0 = blockIdx.x * BM, n0 = blockIdx.y * BN;
  f32x4 acc[FM][FN] = {};
  gemm_phase<BM, BN>(A + (u64)m0 * K, Bt + (u64)n0 * K, K, lA, lB, tid, lane, wm, wn, acc);
#pragma unroll
  for (int fm = 0; fm < FM; ++fm) {
#pragma unroll
    for (int fn = 0; fn < FN; ++fn) {
#pragma unroll
      for (int r = 0; r < 4; ++r) {
        int m = m0 + wm * (BM / 2) + fm * 16 + ((lane >> 4) << 2) + r;
        int n = n0 + wn * (BN / 2) + fn * 16 + (lane & 15);
        float v = acc[fm][fn][r];
        if constexpr (VAR == 0) {
          ob[(u64)m * 512 + n] = f2b(v + bias1[n]);
        } else if constexpr (VAR == 1) {
          if (n < N) {
            int tt = m >> 7, b = m & 127;
            float val = (tt < caplen[b] - 1) ? (v + bias1[n]) : 0.0f;
            o1[((u64)b * 51 + tt) * 18022 + n] = val;
          }
        } else if constexpr (VAR == 3) {
          if (n < 512) ob[m * 512 + n] = f2b(v + bias1[n]);
          else o2[m * 512 + (n - 512)] = v + bias2[n - 512];
        } else if constexpr (VAR == 5) {
          int og = ((n & 3) << 9) | (n >> 2);  // interleaved-gate bias index
          o1[(u64)m * 2048 + n] = v + bias1[og] + bias2[og];
        }
      }
    }
  }
}

// ---------------- grid barrier (device-scope) ----------------
DEV void gbar(u32* cnt, u32* gen, u32 target) {
  __syncthreads();
  if (threadIdx.x == 0) {
    __threadfence();  // flush my writes toward device scope
    u32 t = __hip_atomic_fetch_add(cnt, 1u, __ATOMIC_ACQ_REL, __HIP_MEMORY_SCOPE_AGENT);
    if (t == gridDim.x - 1) {
      __hip_atomic_store(cnt, 0u, __ATOMIC_RELAXED, __HIP_MEMORY_SCOPE_AGENT);
      __hip_atomic_fetch_add(gen, 1u, __ATOMIC_RELEASE, __HIP_MEMORY_SCOPE_AGENT);
    } else {
      while (__hip_atomic_load(gen, __ATOMIC_ACQUIRE, __HIP_MEMORY_SCOPE_AGENT) < target)
        __builtin_amdgcn_s_sleep(2);
    }
    __threadfence();  // invalidate stale lines before consuming peers' writes
  }
  __syncthreads();
}

// ---------------- persistent 51-step decoder loop ----------------
__launch_bounds__(256)
__global__ void loop_k(const u16* __restrict__ att1, const u16* __restrict__ cat,
                       const u16* __restrict__ wihenc, const float* __restrict__ pre,
                       const u16* __restrict__ enc16,
                       const float* __restrict__ bdec, const float* __restrict__ bfb,
                       const float* __restrict__ wfull,
                       float* __restrict__ att2g, float* __restrict__ gateg,
                       u16* __restrict__ ybuf,
                       float* __restrict__ cst, u16* __restrict__ hbf0, u16* __restrict__ hbf1,
                       u16* __restrict__ hall, float* __restrict__ out_alpha,
                       const int* __restrict__ caplen, u32* __restrict__ bar) {
  __shared__ __align__(16) char smem[16384];
  const int bid = blockIdx.x, tid = threadIdx.x, lane = tid & 63;
  const int wm = (tid >> 6) >> 1, wn = (tid >> 6) & 1;
  u32* cnt = bar; u32* gen = bar + 32;
  u32 bgen = 0;
  u16* hc = hbf0; u16* hnx = hbf1;

  for (int t = 0; t < 51; ++t) {
    // ---- P1: att2|gate = h @ [Wdec^T | Wfb^T]  (M=128,N=2560,K=512) ----
    if (bid < 80) {
      u16* lA = (u16*)smem; u16* lB = lA + 64 * 32;
      int m0 = (bid & 1) * 64, n0 = (bid >> 1) * 64;
      f32x4 acc[2][2] = {};
      gemm_phase<64, 64>(hc + (u64)m0 * 512, cat + (u64)n0 * 512, 512, lA, lB, tid, lane, wm, wn, acc);
#pragma unroll
      for (int fm = 0; fm < 2; ++fm)
#pragma unroll
        for (int fn = 0; fn < 2; ++fn)
#pragma unroll
          for (int r = 0; r < 4; ++r) {
            int m = m0 + wm * 32 + fm * 16 + ((lane >> 4) << 2) + r;
            int n = n0 + wn * 32 + fn * 16 + (lane & 15);
            float v = acc[fm][fn][r];
            if (n < 512) att2g[m * 512 + n] = v + bdec[n];
            else gateg[m * 2048 + (n - 512)] = sigm(v + bfb[n - 512]);
          }
    }
    gbar(cnt, gen, ++bgen);

    // ---- P2: e + softmax + awe-half + y  (block = (b, half)) ----
    {
      int b = bid >> 1, half = bid & 1;
      float* s_e = (float*)smem;        // 196
      float* s_red = s_e + 196;         // 8
      float* s_al = s_red + 8;          // 196
      float a2r[8], wr[8];
      {
        const float* pa = att2g + b * 512 + lane * 8;
        const float* pw = wfull + lane * 8;
#pragma unroll
        for (int j = 0; j < 8; ++j) { a2r[j] = pa[j]; wr[j] = pw[j]; }
      }
      int wave = tid >> 6;
      for (int p = wave; p < 196; p += 4) {
        const u16* row = att1 + ((u64)b * 196 + p) * 512 + lane * 8;
        u32x4 q = *(const u32x4*)row;
        float acc = 0.f;
#pragma unroll
        for (int j = 0; j < 4; ++j) {
          u32 w2 = q[j];
          float v0 = b2f((u16)w2) + a2r[2 * j];
          float v1 = b2f((u16)(w2 >> 16)) + a2r[2 * j + 1];
          acc += fmaxf(v0, 0.f) * wr[2 * j] + fmaxf(v1, 0.f) * wr[2 * j + 1];
        }
#pragma unroll
        for (int off = 32; off; off >>= 1) acc += __shfl_xor(acc, off);
        if (lane == 0) s_e[p] = acc;
      }
      __syncthreads();
      float v = (tid < 196) ? s_e[tid] : -1e30f;
      float mx = v;
#pragma unroll
      for (int off = 32; off; off >>= 1) mx = fmaxf(mx, __shfl_xor(mx, off));
      if (lane == 0) s_red[wave] = mx;
      __syncthreads();
      mx = fmaxf(fmaxf(s_red[0], s_red[1]), fmaxf(s_red[2], s_red[3]));
      float ex = (tid < 196) ? __expf(v - mx) : 0.f;
      float sm = ex;
#pragma unroll
      for (int off = 32; off; off >>= 1) sm += __shfl_xor(sm, off);
      if (lane == 0) s_red[4 + wave] = sm;
      __syncthreads();
      sm = s_red[4] + s_red[5] + s_red[6] + s_red[7];
      if (tid < 196) s_al[tid] = ex / sm;
      __syncthreads();
      if (half == 0 && tid < 196) {
        bool act = t < caplen[b] - 1;
        out_alpha[((u64)b * 51 + t) * 196 + tid] = act ? s_al[tid] : 0.f;
      }
      // awe over this half's 1024 cols (4 per thread)
      float aw0 = 0, aw1 = 0, aw2 = 0, aw3 = 0;
      const u16* base = enc16 + (u64)b * 196 * 2048 + half * 1024 + tid * 4;
#pragma unroll 4
      for (int p = 0; p < 196; ++p) {
        u32x2 q = *(const u32x2*)(base + (u64)p * 2048);
        float ap = s_al[p];
        aw0 += ap * b2f((u16)q[0]); aw1 += ap * b2f((u16)(q[0] >> 16));
        aw2 += ap * b2f((u16)q[1]); aw3 += ap * b2f((u16)(q[1] >> 16));
      }
      const float* gr = gateg + b * 2048 + half * 1024 + tid * 4;
      u32 w0 = (u32)f2b(aw0 * gr[0]) | ((u32)f2b(aw1 * gr[1]) << 16);
      u32 w1 = (u32)f2b(aw2 * gr[2]) | ((u32)f2b(aw3 * gr[3]) << 16);
      u16* yp = ybuf + b * 2048 + half * 1024 + tid * 4;
      *(u32*)yp = w0; *(u32*)(yp + 2) = w1;
    }
    gbar(cnt, gen, ++bgen);

    // ---- P3: gates GEMM (K=2048 y + K=512 h) + fused LSTM ----
    if (bid < 64) {
      u16* lA = (u16*)smem; u16* lB = lA + 64 * 32;
      int m0 = (bid & 1) * 64, n0 = (bid >> 1) * 64;
      f32x4 acc[2][2] = {};
      gemm_phase<64, 64>(ybuf + (u64)m0 * 2048, wihenc + (u64)n0 * 2048, 2048, lA, lB, tid, lane, wm, wn, acc);
      gemm_phase<64, 64>(hc + (u64)m0 * 512, cat + (u64)2560 * 512 + (u64)n0 * 512, 512, lA, lB, tid, lane, wm, wn, acc);
      __syncthreads();
      float* gbuf = (float*)smem;  // 64x64 f32
      const float* prow = pre + ((u64)t * 128 + m0) * 2048 + n0;
#pragma unroll
      for (int fm = 0; fm < 2; ++fm)
#pragma unroll
        for (int fn = 0; fn < 2; ++fn)
#pragma unroll
          for (int r = 0; r < 4; ++r) {
            int ml = wm * 32 + fm * 16 + ((lane >> 4) << 2) + r;
            int nl = wn * 32 + fn * 16 + (lane & 15);
            gbuf[ml * 64 + nl] = acc[fm][fn][r] + prow[(u64)ml * 2048 + nl];
          }
      __syncthreads();
#pragma unroll
      for (int j = 0; j < 4; ++j) {
        int l = tid + 256 * j;
        int lm = l >> 4, ld = l & 15;
        int b = m0 + lm, d = (n0 >> 2) + ld;
        const float* gq = gbuf + lm * 64 + ld * 4;
        float ig = gq[0], fg = gq[1], gg = gq[2], og = gq[3];
        float cp = cst[b * 512 + d];
        float cn = sigm(fg) * cp + sigm(ig) * tanhf(gg);
        float hv = sigm(og) * tanhf(cn);
        cst[b * 512 + d] = cn;
        u16 hb = f2b(hv);
        hnx[b * 512 + d] = hb;
        hall[((u64)t * 128 + b) * 512 + d] = hb;
      }
    }
    gbar(cnt, gen, ++bgen);
    u16* tmp = hc; hc = hnx; hnx = tmp;
  }
}

// ---------------- small prep kernels ----------------
__launch_bounds__(64)
__global__ void init_bar_k(u32* bar) { bar[threadIdx.x] = 0; }

__launch_bounds__(256)
__global__ void conv_cvt_k(u16* __restrict__ dst, const float* __restrict__ src,
                           int cols, int src_ld, int src_off, int ileave) {
  int r = blockIdx.x;
  int c = blockIdx.y * 256 + threadIdx.x;
  int rd = ileave ? ((r & 511) * 4 + (r >> 9)) : r;
  if (c < cols) dst[(u64)rd * cols + c] = f2b(src[(u64)r * src_ld + src_off + c]);
}

__launch_bounds__(256)
__global__ void transpose_cvt_k(u16* __restrict__ dst, const float* __restrict__ src, int R, int C) {
  __shared__ u16 tile[32][33];
  int c0 = blockIdx.x * 32, r0 = blockIdx.y * 32;
  int tx = threadIdx.x & 31, ty = threadIdx.x >> 5;
#pragma unroll
  for (int i = 0; i < 4; ++i) {
    int r = r0 + ty + i * 8, c = c0 + tx;
    u16 v = 0;
    if (r < R && c < C) v = f2b(src[(u64)r * C + c]);
    tile[ty + i * 8][tx] = v;
  }
  __syncthreads();
#pragma unroll
  for (int i = 0; i < 4; ++i) {
    int c = c0 + ty + i * 8, r = r0 + tx;
    if (c < C && r < R) dst[(u64)c * R + r] = tile[tx][ty + i * 8];
  }
}

__launch_bounds__(256)
__global__ void emb_gather_k(u16* __restrict__ dst, const float* __restrict__ table,
                             const int* __restrict__ caps) {
  int r = blockIdx.x;  // t*128 + b
  int c = blockIdx.y * 256 + threadIdx.x;
  int tt = r >> 7, b = r & 127;
  int tok = caps[b * 52 + tt];
  dst[(u64)r * 512 + c] = f2b(table[(u64)tok * 512 + c]);
}

__launch_bounds__(256)
__global__ void mean_k(u16* __restrict__ meanb, const u16* __restrict__ enc16) {
  int b = blockIdx.x;
  int e0 = (blockIdx.y * 256 + threadIdx.x) * 2;
  float s0 = 0.f, s1 = 0.f;
  const u16* p = enc16 + (u64)b * 196 * 2048 + e0;
  for (int pp = 0; pp < 196; ++pp) {
    u32 v = *(const u32*)(p + (u64)pp * 2048);
    s0 += b2f((u16)v); s1 += b2f((u16)(v >> 16));
  }
  const float inv = 1.0f / 196.0f;
  u32 o = (u32)f2b(s0 * inv) | ((u32)f2b(s1 * inv) << 16);
  *(u32*)(meanb + (u64)b * 2048 + e0) = o;
}

// ------------------------------------------------------------------
extern "C" void kernel_launch(void* const* d_in, const int* in_sizes, int n_in,
                              void* d_out, int out_size, void* d_ws, size_t ws_size,
                              hipStream_t stream) {
  const float* enc    = (const float*)d_in[0];
  const int*   caps   = (const int*)d_in[1];
  const int*   caplen = (const int*)d_in[2];
  const float* embt   = (const float*)d_in[3];
  const float* Wenc   = (const float*)d_in[4];
  const float* benc   = (const float*)d_in[5];
  const float* Wdec   = (const float*)d_in[6];
  const float* bdec   = (const float*)d_in[7];
  const float* wfull  = (const float*)d_in[8];
  const float* Winh   = (const float*)d_in[10];
  const float* binh   = (const float*)d_in[11];
  const float* Winc   = (const float*)d_in[12];
  const float* binc   = (const float*)d_in[13];
  const float* Wfb    = (const float*)d_in[14];
  const float* bfb    = (const float*)d_in[15];
  const float* Wih    = (const float*)d_in[16];
  const float* bih    = (const float*)d_in[17];
  const float* Whh    = (const float*)d_in[18];
  const float* bhh    = (const float*)d_in[19];
  const float* Wfc    = (const float*)d_in[20];
  const float* bfc    = (const float*)d_in[21];
  float* out = (float*)d_out;
  float* out_alpha = out + 117647616ull;

  char* ws = (char*)d_ws;
  u16*   att1   = (u16*)(ws + 0);            // 25088x512 bf16
  u16*   wenc_t = (u16*)(ws + 25690112);     // 512x2048
  u16*   cat    = (u16*)(ws + 27787264);     // 4608x512: Wdec^T | Wfb^T | Whh'(ileaved)
  u16*   wihenc = (u16*)(ws + 32505856);     // 2048x2048 (ileaved rows)
  u16*   wihemb = (u16*)(ws + 40894464);     // 2048x512  (ileaved rows)
  u16*   wfct   = (u16*)(ws + 42991616);     // 18022x512
  u16*   winit  = (u16*)(ws + 61446144);     // 1024x2048: Winh^T | Winc^T
  u16*   embq   = (u16*)(ws + 65640448);     // 6528x512
  float* pre    = (float*)(ws + 72325120);   // 6528x2048 f32 (ileaved cols)
  u16*   hall   = (u16*)(ws + 125802496);    // 6528x512
  u16*   meanb  = (u16*)(ws + 132487168);    // 128x2048
  float* cst    = (float*)(ws + 133011456);  // 128x512 f32
  u16*   hbf0   = (u16*)(ws + 133273600);    // 128x512
  u16*   hbf1   = (u16*)(ws + 133404672);    // 128x512
  float* att2g  = (float*)(ws + 133535744);  // 128x512 f32
  float* gateg  = (float*)(ws + 133797888);  // 128x2048 f32
  u16*   ybuf   = (u16*)(ws + 134846464);    // 128x2048
  u32*   bar    = (u32*)(ws + 135370752);    // 512 B
  u16*   enc16  = (u16*)(ws + 135371264);    // 128x196x2048 bf16
  // total ws use: 238,131,712 B

  // ---- one-time prep ----
  init_bar_k<<<1, 64, 0, stream>>>(bar);
  transpose_cvt_k<<<dim3(16, 64), 256, 0, stream>>>(wenc_t, Wenc, 2048, 512);
  transpose_cvt_k<<<dim3(16, 16), 256, 0, stream>>>(cat, Wdec, 512, 512);
  transpose_cvt_k<<<dim3(64, 16), 256, 0, stream>>>(cat + 512 * 512, Wfb, 512, 2048);
  conv_cvt_k<<<dim3(2048, 2), 256, 0, stream>>>(cat + 2560 * 512, Whh, 512, 512, 0, 1);
  conv_cvt_k<<<dim3(2048, 8), 256, 0, stream>>>(wihenc, Wih, 2048, 2560, 512, 1);
  conv_cvt_k<<<dim3(2048, 2), 256, 0, stream>>>(wihemb, Wih, 512, 2560, 0, 1);
  transpose_cvt_k<<<dim3(564, 16), 256, 0, stream>>>(wfct, Wfc, 512, 18022);
  transpose_cvt_k<<<dim3(16, 64), 256, 0, stream>>>(winit, Winh, 2048, 512);
  transpose_cvt_k<<<dim3(16, 64), 256, 0, stream>>>(winit + 512 * 2048, Winc, 2048, 512);
  conv_cvt_k<<<dim3(25088, 8), 256, 0, stream>>>(enc16, enc, 2048, 2048, 0, 0);
  emb_gather_k<<<dim3(6528, 2), 256, 0, stream>>>(embq, embt, caps);
  mean_k<<<dim3(128, 4), 256, 0, stream>>>(meanb, enc16);
  // h0 | c0
  gemm_k<64, 64, 3><<<dim3(2, 16), 256, 0, stream>>>(
      meanb, winit, 2048, 0, binh, binc, nullptr, cst, hbf0, nullptr);
  // att1 = enc @ W_enc_att + b  (bf16)
  gemm_k<128, 128, 0><<<dim3(196, 4), 256, 0, stream>>>(
      enc16, wenc_t, 2048, 0, benc, nullptr, nullptr, nullptr, att1, nullptr);
  // pre = emb @ W_ih_emb^T + b_ih + b_hh  (f32, interleaved cols)
  gemm_k<128, 128, 5><<<dim3(51, 16), 256, 0, stream>>>(
      embq, wihemb, 512, 0, bih, bhh, pre, nullptr, nullptr, nullptr);

  // ---- persistent 51-step loop ----
  loop_k<<<256, 256, 0, stream>>>(att1, cat, wihenc, pre, enc16, bdec, bfb, wfull,
                                  att2g, gateg, ybuf, cst, hbf0, hbf1, hall,
                                  out_alpha, caplen, bar);

  // preds = h_all @ W_fc + b_fc, masked, scattered to (b,t,v)
  gemm_k<128, 128, 1><<<dim3(51, 141), 256, 0, stream>>>(
      hall, wfct, 512, 18022, bfc, nullptr, out, nullptr, nullptr, caplen);
}

// Round 7
// 6106.599 us; speedup vs baseline: 2.3881x; 2.3881x over previous
//
#include <hip/hip_runtime.h>

typedef unsigned short u16;
typedef unsigned int u32;
typedef unsigned long long u64;
typedef __attribute__((ext_vector_type(8))) short short8;
typedef __attribute__((ext_vector_type(4))) float f32x4;
typedef __attribute__((ext_vector_type(4))) u32 u32x4;
typedef __attribute__((ext_vector_type(2))) u32 u32x2;

#define DEV __device__ __forceinline__

DEV u16 f2b(float f) {
  u32 u = __builtin_bit_cast(u32, f);
  return (u16)((u + 0x7fffu + ((u >> 16) & 1u)) >> 16);  // RNE
}
DEV float b2f(u16 h) { u32 u = (u32)h << 16; return __builtin_bit_cast(float, u); }
DEV float sigm(float x) { return 1.0f / (1.0f + __expf(-x)); }

// ------------------------------------------------------------------
// Tiled bf16 MFMA GEMM core, prefetch-depth-2 software pipeline.
// C[M,N] = A[M,K] @ Bt[N,K]^T, f32 accum. 256 threads, 4 waves 2x2.
// Loads for K-slice k+2 are issued while slice k computes.
// ------------------------------------------------------------------
template<int BM, int BN>
DEV void gemm_phase(const u16* __restrict__ A, const u16* __restrict__ Bt, int K,
                    u16* lA, u16* lB, int tid, int lane, int wm, int wn,
                    f32x4 (&acc)[BM/32][BN/32]) {
  constexpr int FM = BM / 32, FN = BN / 32;
  constexpr int CA = BM / 64, CB = BN / 64;  // 16B chunks per thread
  const int KI = K >> 5;
  u32x4 ra[2][CA], rb[2][CB];
#pragma unroll
  for (int s = 0; s < 2; ++s) {
    if (s < KI) {
#pragma unroll
      for (int c = 0; c < CA; ++c) { int i = c * 256 + tid; ra[s][c] = *(const u32x4*)(A + (u64)(i >> 2) * K + s * 32 + (i & 3) * 8); }
#pragma unroll
      for (int c = 0; c < CB; ++c) { int i = c * 256 + tid; rb[s][c] = *(const u32x4*)(Bt + (u64)(i >> 2) * K + s * 32 + (i & 3) * 8); }
    }
  }
  for (int k = 0; k < KI; ++k) {
    const int cur = k & 1;
    __syncthreads();  // previous iter's frag reads done before overwrite
#pragma unroll
    for (int c = 0; c < CA; ++c) { int i = c * 256 + tid; *(u32x4*)(lA + i * 8) = ra[cur][c]; }
#pragma unroll
    for (int c = 0; c < CB; ++c) { int i = c * 256 + tid; *(u32x4*)(lB + i * 8) = rb[cur][c]; }
    __syncthreads();
    if (k + 2 < KI) {  // refill the buffer just freed (distance-2 prefetch)
#pragma unroll
      for (int c = 0; c < CA; ++c) { int i = c * 256 + tid; ra[cur][c] = *(const u32x4*)(A + (u64)(i >> 2) * K + (k + 2) * 32 + (i & 3) * 8); }
#pragma unroll
      for (int c = 0; c < CB; ++c) { int i = c * 256 + tid; rb[cur][c] = *(const u32x4*)(Bt + (u64)(i >> 2) * K + (k + 2) * 32 + (i & 3) * 8); }
    }
    short8 af[FM], bfr[FN];
#pragma unroll
    for (int fm = 0; fm < FM; ++fm)
      af[fm] = *(const short8*)(lA + (wm * (BM / 2) + fm * 16 + (lane & 15)) * 32 + (lane >> 4) * 8);
#pragma unroll
    for (int fn = 0; fn < FN; ++fn)
      bfr[fn] = *(const short8*)(lB + (wn * (BN / 2) + fn * 16 + (lane & 15)) * 32 + (lane >> 4) * 8);
#pragma unroll
    for (int fm = 0; fm < FM; ++fm)
#pragma unroll
      for (int fn = 0; fn < FN; ++fn)
        acc[fm][fn] = __builtin_amdgcn_mfma_f32_16x16x32_bf16(af[fm], bfr[fn], acc[fm][fn], 0, 0, 0);
  }
}

// VAR: 0=att1(bf16 out,+bias)  1=preds(masked f32 to out)  2=att2|gate
//      3=h0|c0                 5=pre(f32, +interleaved biases)
template<int BM, int BN, int VAR>
__launch_bounds__(256)
__global__ void gemm_k(const u16* __restrict__ A, const u16* __restrict__ Bt, int K,
                       int N,
                       const float* __restrict__ bias1, const float* __restrict__ bias2,
                       float* __restrict__ o1, float* __restrict__ o2,
                       u16* __restrict__ ob,
                       const int* __restrict__ caplen) {
  constexpr int FM = BM / 32, FN = BN / 32;
  __shared__ __align__(16) u16 lA[BM * 32];
  __shared__ __align__(16) u16 lB[BN * 32];
  const int tid = threadIdx.x, lane = tid & 63;
  const int wm = (tid >> 6) >> 1, wn = (tid >> 6) & 1;
  const int m0 = blockIdx.x * BM, n0 = blockIdx.y * BN;
  f32x4 acc[FM][FN] = {};
  gemm_phase<BM, BN>(A + (u64)m0 * K, Bt + (u64)n0 * K, K, lA, lB, tid, lane, wm, wn, acc);
#pragma unroll
  for (int fm = 0; fm < FM; ++fm) {
#pragma unroll
    for (int fn = 0; fn < FN; ++fn) {
#pragma unroll
      for (int r = 0; r < 4; ++r) {
        int m = m0 + wm * (BM / 2) + fm * 16 + ((lane >> 4) << 2) + r;
        int n = n0 + wn * (BN / 2) + fn * 16 + (lane & 15);
        float v = acc[fm][fn][r];
        if constexpr (VAR == 0) {
          ob[(u64)m * 512 + n] = f2b(v + bias1[n]);
        } else if constexpr (VAR == 1) {
          if (n < N) {
            int tt = m >> 7, b = m & 127;
            float val = (tt < caplen[b] - 1) ? (v + bias1[n]) : 0.0f;
            o1[((u64)b * 51 + tt) * 18022 + n] = val;
          }
        } else if constexpr (VAR == 2) {
          if (n < 512) o1[m * 512 + n] = v + bias1[n];
          else o2[m * 2048 + (n - 512)] = sigm(v + bias2[n - 512]);
        } else if constexpr (VAR == 3) {
          if (n < 512) ob[m * 512 + n] = f2b(v + bias1[n]);
          else o2[m * 512 + (n - 512)] = v + bias2[n - 512];
        } else if constexpr (VAR == 5) {
          int og = ((n & 3) << 9) | (n >> 2);  // interleaved-gate bias index
          o1[(u64)m * 2048 + n] = v + bias1[og] + bias2[og];
        }
      }
    }
  }
}

// ---------------- gates GEMM (K=2048 y + K=512 h) + fused LSTM ----------------
// 64 blocks: tile 64x64 of the 128x2048 interleaved-gate output.
__launch_bounds__(256)
__global__ void gates_lstm_k(const u16* __restrict__ ybuf, const u16* __restrict__ wihenc,
                             const u16* __restrict__ hc, const u16* __restrict__ whh,
                             const float* __restrict__ pre_t,
                             float* __restrict__ cst, u16* __restrict__ hnx,
                             u16* __restrict__ hall_t) {
  __shared__ __align__(16) char smem[16384];
  const int tid = threadIdx.x, lane = tid & 63;
  const int wm = (tid >> 6) >> 1, wn = (tid >> 6) & 1;
  const int m0 = (blockIdx.x & 1) * 64, n0 = (blockIdx.x >> 1) * 64;
  u16* lA = (u16*)smem; u16* lB = lA + 64 * 32;
  f32x4 acc[2][2] = {};
  gemm_phase<64, 64>(ybuf + (u64)m0 * 2048, wihenc + (u64)n0 * 2048, 2048, lA, lB, tid, lane, wm, wn, acc);
  gemm_phase<64, 64>(hc + (u64)m0 * 512, whh + (u64)n0 * 512, 512, lA, lB, tid, lane, wm, wn, acc);
  __syncthreads();
  float* gbuf = (float*)smem;  // 64x64 f32
  const float* prow = pre_t + (u64)m0 * 2048 + n0;
#pragma unroll
  for (int fm = 0; fm < 2; ++fm)
#pragma unroll
    for (int fn = 0; fn < 2; ++fn)
#pragma unroll
      for (int r = 0; r < 4; ++r) {
        int ml = wm * 32 + fm * 16 + ((lane >> 4) << 2) + r;
        int nl = wn * 32 + fn * 16 + (lane & 15);
        gbuf[ml * 64 + nl] = acc[fm][fn][r] + prow[(u64)ml * 2048 + nl];
      }
  __syncthreads();
#pragma unroll
  for (int j = 0; j < 4; ++j) {
    int l = tid + 256 * j;
    int lm = l >> 4, ld = l & 15;
    int b = m0 + lm, d = (n0 >> 2) + ld;
    const float* gq = gbuf + lm * 64 + ld * 4;
    float ig = gq[0], fg = gq[1], gg = gq[2], og = gq[3];
    float cp = cst[b * 512 + d];
    float cn = sigm(fg) * cp + sigm(ig) * tanhf(gg);
    float hv = sigm(og) * tanhf(cn);
    cst[b * 512 + d] = cn;
    u16 hb = f2b(hv);
    hnx[b * 512 + d] = hb;
    hall_t[(u64)b * 512 + d] = hb;
  }
}

// e = relu(att1 + att2) . w_full -> softmax over p -> alpha (ws + masked out)
__launch_bounds__(256)
__global__ void alpha_k(const u16* __restrict__ att1, const float* __restrict__ att2,
                        const float* __restrict__ wfull,
                        float* __restrict__ alpha_ws, float* __restrict__ out_alpha,
                        const int* __restrict__ caplen, int t) {
  int b = blockIdx.x;
  __shared__ float s_e[196];
  __shared__ float s_red[8];
  int tid = threadIdx.x, lane = tid & 63, wave = tid >> 6;
  float a2r[8], wr[8];
  {
    const float* pa = att2 + b * 512 + lane * 8;
    const float* pw = wfull + lane * 8;
#pragma unroll
    for (int j = 0; j < 8; ++j) { a2r[j] = pa[j]; wr[j] = pw[j]; }
  }
  for (int p = wave; p < 196; p += 4) {
    const u16* row = att1 + ((u64)b * 196 + p) * 512 + lane * 8;
    u32x4 q = *(const u32x4*)row;
    float acc = 0.f;
#pragma unroll
    for (int j = 0; j < 4; ++j) {
      u32 w2 = q[j];
      float v0 = b2f((u16)w2) + a2r[2 * j];
      float v1 = b2f((u16)(w2 >> 16)) + a2r[2 * j + 1];
      acc += fmaxf(v0, 0.f) * wr[2 * j] + fmaxf(v1, 0.f) * wr[2 * j + 1];
    }
#pragma unroll
    for (int off = 32; off; off >>= 1) acc += __shfl_xor(acc, off);
    if (lane == 0) s_e[p] = acc;
  }
  __syncthreads();
  float v = (tid < 196) ? s_e[tid] : -1e30f;
  float mx = v;
#pragma unroll
  for (int off = 32; off; off >>= 1) mx = fmaxf(mx, __shfl_xor(mx, off));
  if (lane == 0) s_red[wave] = mx;
  __syncthreads();
  mx = fmaxf(fmaxf(s_red[0], s_red[1]), fmaxf(s_red[2], s_red[3]));
  float ex = (tid < 196) ? __expf(v - mx) : 0.f;
  float sm = ex;
#pragma unroll
  for (int off = 32; off; off >>= 1) sm += __shfl_xor(sm, off);
  if (lane == 0) s_red[4 + wave] = sm;
  __syncthreads();
  sm = s_red[4] + s_red[5] + s_red[6] + s_red[7];
  if (tid < 196) {
    float a = ex / sm;
    alpha_ws[b * 196 + tid] = a;
    bool act = t < caplen[b] - 1;
    out_alpha[((u64)b * 51 + t) * 196 + tid] = act ? a : 0.f;
  }
}

// y = gate * (alpha . enc): grid (128 b, 4 quarters) x 256 thr, 2 cols/thread.
// 8-deep load batching for memory-level parallelism.
__launch_bounds__(256)
__global__ void awe_y_k(const u16* __restrict__ enc16, const float* __restrict__ alpha_ws,
                        const float* __restrict__ gate, u16* __restrict__ y) {
  int b = blockIdx.x;
  int col = blockIdx.y * 512 + threadIdx.x * 2;
  __shared__ float s_a[196];
  if (threadIdx.x < 196) s_a[threadIdx.x] = alpha_ws[b * 196 + threadIdx.x];
  __syncthreads();
  float acc0 = 0.f, acc1 = 0.f;
  const u16* base = enc16 + (u64)b * 196 * 2048 + col;
  int p = 0;
  for (; p + 8 <= 196; p += 8) {
    u32 v[8];
#pragma unroll
    for (int j = 0; j < 8; ++j) v[j] = *(const u32*)(base + (u64)(p + j) * 2048);
#pragma unroll
    for (int j = 0; j < 8; ++j) {
      float a = s_a[p + j];
      acc0 += a * b2f((u16)v[j]);
      acc1 += a * b2f((u16)(v[j] >> 16));
    }
  }
  for (; p < 196; ++p) {
    u32 v = *(const u32*)(base + (u64)p * 2048);
    float a = s_a[p];
    acc0 += a * b2f((u16)v);
    acc1 += a * b2f((u16)(v >> 16));
  }
  const float* g = gate + b * 2048 + col;
  u32 w = (u32)f2b(acc0 * g[0]) | ((u32)f2b(acc1 * g[1]) << 16);
  *(u32*)(y + (u64)b * 2048 + col) = w;
}

// ---------------- small prep kernels ----------------
__launch_bounds__(256)
__global__ void conv_cvt_k(u16* __restrict__ dst, const float* __restrict__ src,
                           int cols, int src_ld, int src_off, int ileave) {
  int r = blockIdx.x;
  int c = blockIdx.y * 256 + threadIdx.x;
  int rd = ileave ? ((r & 511) * 4 + (r >> 9)) : r;
  if (c < cols) dst[(u64)rd * cols + c] = f2b(src[(u64)r * src_ld + src_off + c]);
}

__launch_bounds__(256)
__global__ void transpose_cvt_k(u16* __restrict__ dst, const float* __restrict__ src, int R, int C) {
  __shared__ u16 tile[32][33];
  int c0 = blockIdx.x * 32, r0 = blockIdx.y * 32;
  int tx = threadIdx.x & 31, ty = threadIdx.x >> 5;
#pragma unroll
  for (int i = 0; i < 4; ++i) {
    int r = r0 + ty + i * 8, c = c0 + tx;
    u16 v = 0;
    if (r < R && c < C) v = f2b(src[(u64)r * C + c]);
    tile[ty + i * 8][tx] = v;
  }
  __syncthreads();
#pragma unroll
  for (int i = 0; i < 4; ++i) {
    int c = c0 + ty + i * 8, r = r0 + tx;
    if (c < C && r < R) dst[(u64)c * R + r] = tile[tx][ty + i * 8];
  }
}

__launch_bounds__(256)
__global__ void emb_gather_k(u16* __restrict__ dst, const float* __restrict__ table,
                             const int* __restrict__ caps) {
  int r = blockIdx.x;  // t*128 + b
  int c = blockIdx.y * 256 + threadIdx.x;
  int tt = r >> 7, b = r & 127;
  int tok = caps[b * 52 + tt];
  dst[(u64)r * 512 + c] = f2b(table[(u64)tok * 512 + c]);
}

__launch_bounds__(256)
__global__ void mean_k(u16* __restrict__ meanb, const u16* __restrict__ enc16) {
  int b = blockIdx.x;
  int e0 = (blockIdx.y * 256 + threadIdx.x) * 2;
  float s0 = 0.f, s1 = 0.f;
  const u16* p = enc16 + (u64)b * 196 * 2048 + e0;
  for (int pp = 0; pp < 196; ++pp) {
    u32 v = *(const u32*)(p + (u64)pp * 2048);
    s0 += b2f((u16)v); s1 += b2f((u16)(v >> 16));
  }
  const float inv = 1.0f / 196.0f;
  u32 o = (u32)f2b(s0 * inv) | ((u32)f2b(s1 * inv) << 16);
  *(u32*)(meanb + (u64)b * 2048 + e0) = o;
}

// ------------------------------------------------------------------
extern "C" void kernel_launch(void* const* d_in, const int* in_sizes, int n_in,
                              void* d_out, int out_size, void* d_ws, size_t ws_size,
                              hipStream_t stream) {
  const float* enc    = (const float*)d_in[0];
  const int*   caps   = (const int*)d_in[1];
  const int*   caplen = (const int*)d_in[2];
  const float* embt   = (const float*)d_in[3];
  const float* Wenc   = (const float*)d_in[4];
  const float* benc   = (const float*)d_in[5];
  const float* Wdec   = (const float*)d_in[6];
  const float* bdec   = (const float*)d_in[7];
  const float* wfull  = (const float*)d_in[8];
  const float* Winh   = (const float*)d_in[10];
  const float* binh   = (const float*)d_in[11];
  const float* Winc   = (const float*)d_in[12];
  const float* binc   = (const float*)d_in[13];
  const float* Wfb    = (const float*)d_in[14];
  const float* bfb    = (const float*)d_in[15];
  const float* Wih    = (const float*)d_in[16];
  const float* bih    = (const float*)d_in[17];
  const float* Whh    = (const float*)d_in[18];
  const float* bhh    = (const float*)d_in[19];
  const float* Wfc    = (const float*)d_in[20];
  const float* bfc    = (const float*)d_in[21];
  float* out = (float*)d_out;
  float* out_alpha = out + 117647616ull;

  char* ws = (char*)d_ws;
  u16*   att1   = (u16*)(ws + 0);            // 25088x512 bf16
  u16*   wenc_t = (u16*)(ws + 25690112);     // 512x2048
  u16*   cat    = (u16*)(ws + 27787264);     // 4608x512: Wdec^T | Wfb^T | Whh'(ileaved)
  u16*   wihenc = (u16*)(ws + 32505856);     // 2048x2048 (ileaved rows)
  u16*   wihemb = (u16*)(ws + 40894464);     // 2048x512  (ileaved rows)
  u16*   wfct   = (u16*)(ws + 42991616);     // 18022x512
  u16*   winit  = (u16*)(ws + 61446144);     // 1024x2048: Winh^T | Winc^T
  u16*   embq   = (u16*)(ws + 65640448);     // 6528x512
  float* pre    = (float*)(ws + 72325120);   // 6528x2048 f32 (ileaved cols)
  u16*   hall   = (u16*)(ws + 125802496);    // 6528x512
  u16*   meanb  = (u16*)(ws + 132487168);    // 128x2048
  float* cst    = (float*)(ws + 133011456);  // 128x512 f32
  u16*   hbf0   = (u16*)(ws + 133273600);    // 128x512
  u16*   hbf1   = (u16*)(ws + 133404672);    // 128x512
  float* att2g  = (float*)(ws + 133535744);  // 128x512 f32
  float* gateg  = (float*)(ws + 133797888);  // 128x2048 f32
  u16*   ybuf   = (u16*)(ws + 134846464);    // 128x2048
  float* alphaw = (float*)(ws + 135370752);  // 128x196
  u16*   enc16  = (u16*)(ws + 135471104);    // 128x196x2048 bf16
  // total ws use: ~238 MB

  // ---- one-time prep ----
  transpose_cvt_k<<<dim3(16, 64), 256, 0, stream>>>(wenc_t, Wenc, 2048, 512);
  transpose_cvt_k<<<dim3(16, 16), 256, 0, stream>>>(cat, Wdec, 512, 512);
  transpose_cvt_k<<<dim3(64, 16), 256, 0, stream>>>(cat + 512 * 512, Wfb, 512, 2048);
  conv_cvt_k<<<dim3(2048, 2), 256, 0, stream>>>(cat + 2560 * 512, Whh, 512, 512, 0, 1);
  conv_cvt_k<<<dim3(2048, 8), 256, 0, stream>>>(wihenc, Wih, 2048, 2560, 512, 1);
  conv_cvt_k<<<dim3(2048, 2), 256, 0, stream>>>(wihemb, Wih, 512, 2560, 0, 1);
  transpose_cvt_k<<<dim3(564, 16), 256, 0, stream>>>(wfct, Wfc, 512, 18022);
  transpose_cvt_k<<<dim3(16, 64), 256, 0, stream>>>(winit, Winh, 2048, 512);
  transpose_cvt_k<<<dim3(16, 64), 256, 0, stream>>>(winit + 512 * 2048, Winc, 2048, 512);
  conv_cvt_k<<<dim3(25088, 8), 256, 0, stream>>>(enc16, enc, 2048, 2048, 0, 0);
  emb_gather_k<<<dim3(6528, 2), 256, 0, stream>>>(embq, embt, caps);
  mean_k<<<dim3(128, 4), 256, 0, stream>>>(meanb, enc16);
  // h0 | c0
  gemm_k<64, 64, 3><<<dim3(2, 16), 256, 0, stream>>>(
      meanb, winit, 2048, 0, binh, binc, nullptr, cst, hbf0, nullptr);
  // att1 = enc @ W_enc_att + b  (bf16)
  gemm_k<128, 128, 0><<<dim3(196, 4), 256, 0, stream>>>(
      enc16, wenc_t, 2048, 0, benc, nullptr, nullptr, nullptr, att1, nullptr);
  // pre = emb @ W_ih_emb^T + b_ih + b_hh  (f32, interleaved cols)
  gemm_k<128, 128, 5><<<dim3(51, 16), 256, 0, stream>>>(
      embq, wihemb, 512, 0, bih, bhh, pre, nullptr, nullptr, nullptr);

  // ---- recurrent loop (4 kernels/step) ----
  u16* hc = hbf0;
  u16* hn = hbf1;
  for (int t = 0; t < 51; ++t) {
    // att2 | gate = h @ [Wdec^T | sigmoid(Wfb^T)]
    gemm_k<64, 64, 2><<<dim3(2, 40), 256, 0, stream>>>(
        hc, cat, 512, 0, bdec, bfb, att2g, gateg, nullptr, nullptr);
    alpha_k<<<128, 256, 0, stream>>>(att1, att2g, wfull, alphaw, out_alpha, caplen, t);
    awe_y_k<<<dim3(128, 4), 256, 0, stream>>>(enc16, alphaw, gateg, ybuf);
    gates_lstm_k<<<64, 256, 0, stream>>>(
        ybuf, wihenc, hc, cat + 2560 * 512, pre + (u64)t * 128 * 2048,
        cst, hn, hall + (u64)t * 128 * 512);
    u16* tmp = hc; hc = hn; hn = tmp;
  }

  // preds = h_all @ W_fc + b_fc, masked, scattered to (b,t,v)
  gemm_k<128, 128, 1><<<dim3(51, 141), 256, 0, stream>>>(
      hall, wfct, 512, 18022, bfc, nullptr, out, nullptr, nullptr, caplen);
}